// Round 1
// baseline (947.949 us; speedup 1.0000x reference)
//
#include <hip/hip_runtime.h>

#define LSTM_B 4096
#define LSTM_S 512
#define LSTM_H 50

__device__ __forceinline__ float fast_sigmoid(float v) {
    return 1.0f / (1.0f + __expf(-v));
}
// robust tanh via exp: saturates correctly for large |v|
__device__ __forceinline__ float fast_tanh(float v) {
    return 1.0f - 2.0f / (__expf(2.0f * v) + 1.0f);
}

// One wave (64 lanes) per batch element. Lane j<50 owns hidden unit j:
// it computes the i,f,g,o gate dots for unit j (W rows j, 50+j, 100+j, 150+j
// held in registers), updates c_j, h_j, and publishes h_j via LDS broadcast.
// Single-wave block => barriers are near-free; they also force the
// lgkmcnt drain that makes the h_lds hand-off safe.
__global__ __launch_bounds__(64, 2) void lstm_fused_kernel(
    const float* __restrict__ x,      // [B, S] (I==1)
    const float* __restrict__ W_ih,   // [200, 1]
    const float* __restrict__ W_hh,   // [200, 50]
    const float* __restrict__ b_ih,   // [200]
    const float* __restrict__ b_hh,   // [200]
    const float* __restrict__ W_fc,   // [1, 50]
    const float* __restrict__ b_fc,   // [1]
    float* __restrict__ out)          // [B]
{
    const int b = blockIdx.x;
    const int j = threadIdx.x;                    // 0..63
    const int jc = (j < LSTM_H) ? j : 0;          // clamp idle lanes in-bounds

    __shared__ __align__(16) float x_lds[LSTM_S];
    __shared__ __align__(16) float h_lds[LSTM_H + 2];

    // stage x[b,:] into LDS, coalesced float4 (512 floats = 128 float4)
    {
        const float4* xg = reinterpret_cast<const float4*>(x + (size_t)b * LSTM_S);
        float4* xs = reinterpret_cast<float4*>(x_lds);
        xs[j]      = xg[j];
        xs[j + 64] = xg[j + 64];
    }
    if (j < LSTM_H) h_lds[j] = 0.0f;              // h0 = 0

    // per-lane weights: 4 gate rows of W_hh (one-time, L2-served)
    float w[4][LSTM_H];
    float wih[4], bias[4];
    #pragma unroll
    for (int g = 0; g < 4; ++g) {
        const int row = g * LSTM_H + jc;
        const float* wr = W_hh + row * LSTM_H;
        #pragma unroll
        for (int k = 0; k < LSTM_H; ++k) w[g][k] = wr[k];
        wih[g]  = W_ih[row];                      // I == 1
        bias[g] = b_ih[row] + b_hh[row];
    }

    float c  = 0.0f;
    float hj = 0.0f;

    __syncthreads();

    const float4* h4 = reinterpret_cast<const float4*>(h_lds);

    for (int s = 0; s < LSTM_S; ++s) {
        const float xs = x_lds[s];
        float zi = fmaf(xs, wih[0], bias[0]);
        float zf = fmaf(xs, wih[1], bias[1]);
        float zg = fmaf(xs, wih[2], bias[2]);
        float zo = fmaf(xs, wih[3], bias[3]);

        #pragma unroll
        for (int kk = 0; kk < 12; ++kk) {         // k = 0..47 via float4 broadcast
            const float4 hv = h4[kk];
            const int k0 = 4 * kk;
            zi = fmaf(hv.x, w[0][k0+0], zi); zi = fmaf(hv.y, w[0][k0+1], zi);
            zi = fmaf(hv.z, w[0][k0+2], zi); zi = fmaf(hv.w, w[0][k0+3], zi);
            zf = fmaf(hv.x, w[1][k0+0], zf); zf = fmaf(hv.y, w[1][k0+1], zf);
            zf = fmaf(hv.z, w[1][k0+2], zf); zf = fmaf(hv.w, w[1][k0+3], zf);
            zg = fmaf(hv.x, w[2][k0+0], zg); zg = fmaf(hv.y, w[2][k0+1], zg);
            zg = fmaf(hv.z, w[2][k0+2], zg); zg = fmaf(hv.w, w[2][k0+3], zg);
            zo = fmaf(hv.x, w[3][k0+0], zo); zo = fmaf(hv.y, w[3][k0+1], zo);
            zo = fmaf(hv.z, w[3][k0+2], zo); zo = fmaf(hv.w, w[3][k0+3], zo);
        }
        {                                         // tail k = 48, 49
            const float h48 = h_lds[48], h49 = h_lds[49];
            zi = fmaf(h48, w[0][48], zi); zi = fmaf(h49, w[0][49], zi);
            zf = fmaf(h48, w[1][48], zf); zf = fmaf(h49, w[1][49], zf);
            zg = fmaf(h48, w[2][48], zg); zg = fmaf(h49, w[2][49], zg);
            zo = fmaf(h48, w[3][48], zo); zo = fmaf(h49, w[3][49], zo);
        }

        const float ig = fast_sigmoid(zi);
        const float fg = fast_sigmoid(zf);
        const float gg = fast_tanh(zg);
        const float og = fast_sigmoid(zo);
        c  = fmaf(fg, c, ig * gg);
        hj = og * fast_tanh(c);

        __syncthreads();                          // all lanes done reading h(s-1)
        if (j < LSTM_H) h_lds[j] = hj;
        __syncthreads();                          // h(s) visible
    }

    // out[b] = sigmoid(h_last . W_fc + b_fc), wave-wide shfl reduction
    float contrib = (j < LSTM_H) ? (W_fc[j] * hj) : 0.0f;
    #pragma unroll
    for (int off = 32; off > 0; off >>= 1)
        contrib += __shfl_down(contrib, off);
    if (j == 0) out[b] = fast_sigmoid(contrib + b_fc[0]);
}

extern "C" void kernel_launch(void* const* d_in, const int* in_sizes, int n_in,
                              void* d_out, int out_size, void* d_ws, size_t ws_size,
                              hipStream_t stream) {
    const float* x    = (const float*)d_in[0];
    const float* W_ih = (const float*)d_in[1];
    const float* W_hh = (const float*)d_in[2];
    const float* b_ih = (const float*)d_in[3];
    const float* b_hh = (const float*)d_in[4];
    const float* W_fc = (const float*)d_in[5];
    const float* b_fc = (const float*)d_in[6];
    float* out = (float*)d_out;

    lstm_fused_kernel<<<LSTM_B, 64, 0, stream>>>(x, W_ih, W_hh, b_ih, b_hh,
                                                 W_fc, b_fc, out);
}